// Round 4
// baseline (413.481 us; speedup 1.0000x reference)
//
#include <hip/hip_runtime.h>
#include <math.h>

// NoisyTopKRouter: x[65536,1024] fp32 -> gates[65536,8] + aux_loss.
// R4: full-contiguity staging. One global_load_lds = one 1 KB contiguous
// row-chunk (R3 touched rows in 256 B slivers 4 KB apart -> ~1.7 TB/s eff).
// Single 65 KB buffer, 2-barrier K-loop (stage burst of one block overlaps
// compute of the co-resident block), 2 blocks/CU. k wave-uniform -> weights
// stay on the scalar s_load path. Epilogue verified in R1-R3.

#define N_TOKENS   65536
#define EMBED_DIM  1024
#define NE         8
#define BROWS      64                    // rows per block = lanes
#define CHUNK      256                   // floats per row per chunk (1 KB)
#define NCH        (EMBED_DIM / CHUNK)   // 4
#define RSTRIDE    260                   // 256 + 4 pad floats (16B aligned)
#define NSLOT      64
#define NOISE_EPS  0.2f

#define AS1(p) (const __attribute__((address_space(1))) void*)(p)
#define AS3(p) (__attribute__((address_space(3))) void*)(p)

__global__ __launch_bounds__(256, 2)
void router_kernel(const float* __restrict__ x,
                   const float* __restrict__ eps,
                   const float* __restrict__ wg,
                   const float* __restrict__ wn,
                   float* __restrict__ gates,
                   float* __restrict__ acc /* NSLOT x 16 floats */) {
    __shared__ float tile[BROWS * RSTRIDE];   // 66560 B -> 2 blocks/CU

    const int t    = threadIdx.x;
    const int lane = t & 63;
    const int w    = __builtin_amdgcn_readfirstlane(t >> 6);   // wave 0..3
    const long rowbase = (long)blockIdx.x * BROWS;

    float accg[NE], accn[NE];
#pragma unroll
    for (int e = 0; e < NE; ++e) { accg[e] = 0.f; accn[e] = 0.f; }

    // stage chunk 0: wave w stages rows w*16..w*16+15, one instr per row,
    // each 1 KB fully contiguous in global AND in LDS (base + lane*16).
#pragma unroll
    for (int i = 0; i < 16; ++i) {
        const int r = w * 16 + i;
        const float* gp = x + (rowbase + r) * (long)EMBED_DIM + lane * 4;
        __builtin_amdgcn_global_load_lds(AS1(gp), AS3(&tile[r * RSTRIDE]), 16, 0, 0);
    }

#pragma unroll
    for (int c = 0; c < NCH; ++c) {
        __syncthreads();   // drains vmcnt: chunk c fully staged

        // wave w consumes k-quarter [c*256 + w*64, +64) of row `lane`
        const float4* trow = (const float4*)tile + lane * (RSTRIDE / 4) + w * 16;
        const float* wgc = wg + ((long)c * CHUNK + w * 64) * NE;
        const float* wnc = wn + ((long)c * CHUNK + w * 64) * NE;
#pragma unroll 4
        for (int j = 0; j < 16; ++j) {
            float4 xv = trow[j];
            const float xa[4] = { xv.x, xv.y, xv.z, xv.w };
#pragma unroll
            for (int q = 0; q < 4; ++q) {
                const int k = j * 4 + q;
#pragma unroll
                for (int e = 0; e < NE; ++e) {
                    accg[e] = fmaf(xa[q], wgc[k * NE + e], accg[e]);
                    accn[e] = fmaf(xa[q], wnc[k * NE + e], accn[e]);
                }
            }
        }
        __syncthreads();   // all reads of buffer done; safe to overwrite

        if (c + 1 < NCH) {
#pragma unroll
            for (int i = 0; i < 16; ++i) {
                const int r = w * 16 + i;
                const float* gp = x + (rowbase + r) * (long)EMBED_DIM
                                  + (c + 1) * CHUNK + lane * 4;
                __builtin_amdgcn_global_load_lds(AS1(gp), AS3(&tile[r * RSTRIDE]),
                                                 16, 0, 0);
            }
        }
    }

    // ---- combine 4-way k-split (reuse tile: 12 KB < 65 KB) ----
    float* part = tile;
    if (w != 0) {
#pragma unroll
        for (int e = 0; e < NE; ++e) {
            part[((w - 1) * BROWS + lane) * 16 + e]      = accg[e];
            part[((w - 1) * BROWS + lane) * 16 + NE + e] = accn[e];
        }
    }
    __syncthreads();
    if (w != 0) return;

#pragma unroll
    for (int v = 0; v < 3; ++v)
#pragma unroll
        for (int e = 0; e < NE; ++e) {
            accg[e] += part[(v * BROWS + lane) * 16 + e];
            accn[e] += part[(v * BROWS + lane) * 16 + NE + e];
        }

    // ---- fused epilogue (wave 0, one row per lane) ----
    const long row = rowbase + lane;
    const float* er = eps + row * NE;
    float4 ev0 = *(const float4*)(er);
    float4 ev1 = *(const float4*)(er + 4);
    float epsv[NE] = { ev0.x, ev0.y, ev0.z, ev0.w, ev1.x, ev1.y, ev1.z, ev1.w };

    float noisy[NE];
#pragma unroll
    for (int e = 0; e < NE; ++e) {
        float r = accn[e];
        float sp = fmaxf(r, 0.f) + log1pf(expf(-fabsf(r)));   // stable softplus
        noisy[e] = accg[e] + (sp + NOISE_EPS) * epsv[e];
    }

    int i1 = 0; float v1 = noisy[0];
#pragma unroll
    for (int e = 1; e < NE; ++e) if (noisy[e] > v1) { v1 = noisy[e]; i1 = e; }
    int i2 = -1; float v2 = -INFINITY;
#pragma unroll
    for (int e = 0; e < NE; ++e) if (e != i1 && noisy[e] > v2) { v2 = noisy[e]; i2 = e; }

    float bb = expf(v2 - v1);
    float g2 = bb / (1.f + bb);
    float g1 = 1.f - g2;

    float* gr = gates + row * NE;
    float ov[NE];
#pragma unroll
    for (int e = 0; e < NE; ++e)
        ov[e] = (e == i1) ? g1 : ((e == i2) ? g2 : 0.f);
    *(float4*)(gr)     = make_float4(ov[0], ov[1], ov[2], ov[3]);
    *(float4*)(gr + 4) = make_float4(ov[4], ov[5], ov[6], ov[7]);

    float mx = accg[0];
#pragma unroll
    for (int e = 1; e < NE; ++e) mx = fmaxf(mx, accg[e]);
    float p[NE]; float s = 0.f;
#pragma unroll
    for (int e = 0; e < NE; ++e) { p[e] = expf(accg[e] - mx); s += p[e]; }
    float inv = 1.f / s;

    float vals[16];
#pragma unroll
    for (int e = 0; e < NE; ++e) {
        vals[e]      = p[e] * inv;
        vals[NE + e] = ((i1 == e) ? 1.f : 0.f) + ((i2 == e && g2 > 0.f) ? 1.f : 0.f);
    }
#pragma unroll
    for (int off = 32; off > 0; off >>= 1)
#pragma unroll
        for (int i = 0; i < 16; ++i)
            vals[i] += __shfl_xor(vals[i], off, 64);

    if (lane == 0) {
        float* slot = acc + (blockIdx.x & (NSLOT - 1)) * 16;
#pragma unroll
        for (int i = 0; i < 16; ++i)
            atomicAdd(&slot[i], vals[i]);
    }
}

__global__ void finalize_kernel(const float* __restrict__ acc,
                                float* __restrict__ out_aux) {
    __shared__ float s[16];
    const int t = threadIdx.x;
    if (t < 16) {
        float v = 0.f;
        for (int j = 0; j < NSLOT; ++j) v += acc[j * 16 + t];
        s[t] = v;
    }
    __syncthreads();
    if (t == 0) {
        const float invn = 1.f / (float)N_TOKENS;
        float aux = 0.f;
#pragma unroll
        for (int e = 0; e < NE; ++e)
            aux += (s[e] * invn) * (s[NE + e] * invn);
        *out_aux = (float)NE * aux;
    }
}

extern "C" void kernel_launch(void* const* d_in, const int* in_sizes, int n_in,
                              void* d_out, int out_size, void* d_ws, size_t ws_size,
                              hipStream_t stream) {
    const float* x   = (const float*)d_in[0];
    const float* eps = (const float*)d_in[1];
    const float* wg  = (const float*)d_in[2];
    const float* wn  = (const float*)d_in[3];
    float* out = (float*)d_out;
    float* acc = (float*)d_ws;

    hipMemsetAsync(d_ws, 0, NSLOT * 16 * sizeof(float), stream);

    router_kernel<<<dim3(N_TOKENS / BROWS), dim3(256), 0, stream>>>(
        x, eps, wg, wn, out, acc);
    finalize_kernel<<<dim3(1), dim3(64), 0, stream>>>(acc, out + (out_size - 1));
}